// Round 7
// baseline (65.587 us; speedup 1.0000x reference)
//
#include <hip/hip_runtime.h>
#include <hip/hip_bf16.h>
#include <stdint.h>

typedef __bf16 bf16;
typedef __attribute__((ext_vector_type(8))) __bf16 bf16x8;
typedef __attribute__((ext_vector_type(2))) __bf16 bf16x2;
typedef __attribute__((ext_vector_type(4))) float f32x4;
typedef __attribute__((ext_vector_type(4))) unsigned int u32x4;

#define GLOAD16(gsrc, ldst)                                              \
  __builtin_amdgcn_global_load_lds(                                      \
      (const __attribute__((address_space(1))) unsigned int*)(gsrc),     \
      (__attribute__((address_space(3))) unsigned int*)(ldst), 16, 0, 0)

static constexpr int T_LEN = 4096;
static constexpr int WIN = 16;

__device__ __forceinline__ bf16x8 cvt8(float4 a, float4 b) {
  bf16x8 o;
  o[0] = (bf16)a.x; o[1] = (bf16)a.y; o[2] = (bf16)a.z; o[3] = (bf16)a.w;
  o[4] = (bf16)b.x; o[5] = (bf16)b.y; o[6] = (bf16)b.z; o[7] = (bf16)b.w;
  return o;
}

// ---- cast weights: Wq,Wk,Wv -> wqkv[1536][512], Wp -> wpb[512][512] ----
__global__ __launch_bounds__(256) void prep_kernel(const float* __restrict__ wq,
                                                   const float* __restrict__ wk,
                                                   const float* __restrict__ wv,
                                                   const float* __restrict__ wp,
                                                   bf16* __restrict__ wqkv,
                                                   bf16* __restrict__ wpb) {
  int i = blockIdx.x * 256 + threadIdx.x;  // 131072 threads
  int which = i >> 15;
  int j = i & 32767;
  const float* src = (which == 0) ? wq : (which == 1) ? wk : (which == 2) ? wv : wp;
  bf16* dst = (which < 3) ? (wqkv + (size_t)which * 512 * 512) : wpb;
  const float4* s4 = (const float4*)src + (size_t)j * 2;
  ((bf16x8*)dst)[j] = cvt8(s4[0], s4[1]);
}

// ---- QKV GEMM: C[m][n] = sum_k x[m][k] * Bw[n][k]; A cast fp32->bf16 in-stage ----
__global__ __launch_bounds__(256) void gemm_qkv_kernel(const float* __restrict__ Xf,
                                                       const bf16* __restrict__ Bw,
                                                       bf16* __restrict__ Cb) {
  constexpr int K = 512, BK = 32;
  __shared__ __align__(16) bf16 As[128 * BK];
  __shared__ __align__(16) bf16 Bs[128 * BK];
  const int tid = threadIdx.x;
  const int l = tid & 63;
  const int w = tid >> 6;
  // XCD-aware swizzle: 768 blocks = 96 per XCD
  int bid = blockIdx.x;
  bid = (bid & 7) * 96 + (bid >> 3);
  const int m0 = (bid / 12) * 128;
  const int n0 = (bid % 12) * 128;
  const int arow = tid >> 2;
  const int acol = (tid & 3) * 8;
  const float* Ag = Xf + (size_t)(m0 + arow) * K + acol;
  const bf16* Bg = Bw + (size_t)(n0 + arow) * K + acol;

  const f32x4 zero = {0.f, 0.f, 0.f, 0.f};
  f32x4 acc[4][4];
#pragma unroll
  for (int i = 0; i < 4; ++i)
#pragma unroll
    for (int j = 0; j < 4; ++j) acc[i][j] = zero;

  const int wm = (w >> 1) * 64;
  const int wn = (w & 1) * 64;
  const int frow = l & 15;
  const int fcol = (l >> 4) * 8;

  for (int k0 = 0; k0 < K; k0 += BK) {
    GLOAD16(Bg + k0,          &Bs[tid * 8]);
    GLOAD16(Bg + 64 * K + k0, &Bs[tid * 8 + 2048]);
    {
      const float4* s0 = (const float4*)(Ag + k0);
      const float4* s1 = (const float4*)(Ag + 64 * K + k0);
      float4 a0 = s0[0], a1 = s0[1];
      float4 b0 = s1[0], b1 = s1[1];
      *(bf16x8*)&As[tid * 8] = cvt8(a0, a1);
      *(bf16x8*)&As[tid * 8 + 2048] = cvt8(b0, b1);
    }
    __syncthreads();
    bf16x8 af[4], bfr[4];
#pragma unroll
    for (int mi = 0; mi < 4; ++mi)
      af[mi] = *(const bf16x8*)&As[(wm + mi * 16 + frow) * BK + fcol];
#pragma unroll
    for (int ni = 0; ni < 4; ++ni)
      bfr[ni] = *(const bf16x8*)&Bs[(wn + ni * 16 + frow) * BK + fcol];
#pragma unroll
    for (int mi = 0; mi < 4; ++mi)
#pragma unroll
      for (int ni = 0; ni < 4; ++ni)
        acc[mi][ni] = __builtin_amdgcn_mfma_f32_16x16x32_bf16(af[mi], bfr[ni], acc[mi][ni], 0, 0, 0);
    __syncthreads();
  }

  const int r0 = (l >> 4) * 4;
  const int c0 = l & 15;
#pragma unroll
  for (int mi = 0; mi < 4; ++mi)
#pragma unroll
    for (int ni = 0; ni < 4; ++ni) {
      int row = m0 + wm + mi * 16 + r0;
      int col = n0 + wn + ni * 16 + c0;
#pragma unroll
      for (int r = 0; r < 4; ++r)
        Cb[(size_t)(row + r) * 1536 + col] = (bf16)acc[mi][ni][r];
    }
}

// ---- local attention, MFMA-based; K row-major, V transposed, Q via LDS ----
static constexpr int TCB = 64;
static constexpr int NP = 96;
static constexpr int KST = 72;
static constexpr int NPT = 112;  // Vt col count (96 window + 16 zero halo)

__global__ __launch_bounds__(256) void attn_kernel(const bf16* __restrict__ qkv,
                                                   bf16* __restrict__ aout) {
  __shared__ __align__(16) bf16 Kl[NP * KST];
  __shared__ __align__(16) unsigned short Vt[64 * NPT];  // V^T[d][p]
  __shared__ __align__(16) bf16 QPO[4 * 16 * 72];  // per-wave: Q[16][72] -> P[16][56] -> O[16][72]

  const int tid = threadIdx.x;
  const int wid = tid >> 6;
  const int l = tid & 63;
  const int g = l >> 4;
  const int c = l & 15;

  const int bid = blockIdx.x;  // 1024 = 2 * 8 * 64
  const int chunk = bid & 63;
  const int h = (bid >> 6) & 7;
  const int b = bid >> 9;
  const int t0 = chunk * TCB;
  const int base = b * T_LEN;

  // ---- stage K row-major, V transposed ----
#pragma unroll
  for (int i = 0; i < 3; ++i) {
    int task = tid + i * 256;  // 768 = 96 pos x 8 col-chunks
    int p = task >> 3;
    int c8 = (task & 7) * 8;
    int pg = min(max(t0 - WIN + p, 0), T_LEN - 1);
    const bf16* kr = qkv + (size_t)(base + pg) * 1536 + 512 + h * 64 + c8;
    const bf16* vr = qkv + (size_t)(base + pg) * 1536 + 1024 + h * 64 + c8;
    *(bf16x8*)&Kl[p * KST + c8] = *(const bf16x8*)kr;
    bf16x8 vv = *(const bf16x8*)vr;
#pragma unroll
    for (int e = 0; e < 8; ++e)
      Vt[(c8 + e) * NPT + p] = ((const unsigned short*)&vv)[e];
  }
  // ---- stage Q (coalesced) into per-wave overlay regions ----
#pragma unroll
  for (int i = 0; i < 2; ++i) {
    int task = tid + i * 256;  // 512 = 64 rows x 8 chunks
    int p = task >> 3;
    int c8 = (task & 7) * 8;
    const bf16* qr = qkv + (size_t)(base + t0 + p) * 1536 + h * 64 + c8;
    *(bf16x8*)&QPO[(p >> 4) * 1152 + (p & 15) * 72 + c8] = *(const bf16x8*)qr;
  }
  // zero-fill Vt halo cols p=96..111 (read where P=0; must be finite)
  {
    int d = tid >> 2;
    int p0 = 96 + (tid & 3) * 4;
    *(uint2*)&Vt[d * NPT + p0] = make_uint2(0u, 0u);
  }
  __syncthreads();

  const int tg = t0 + wid * 16;
  const float scale = 0.125f;  // 64^-0.5

  // ---- Q fragments from LDS: k-map (g,e) -> d = 32*kh + 8g + e ----
  bf16* Qw = &QPO[wid * 1152];
  bf16x8 qf0 = *(const bf16x8*)&Qw[c * 72 + g * 8];
  bf16x8 qf1 = *(const bf16x8*)&Qw[c * 72 + 32 + g * 8];

  const f32x4 zero = {0.f, 0.f, 0.f, 0.f};
  const u32x4 zu = {0u, 0u, 0u, 0u};

  // ---- S^T = K @ Q^T ----
  f32x4 st[3];
#pragma unroll
  for (int wt = 0; wt < 3; ++wt) {
    int rk = 16 * wid + 16 * wt + c;
    bf16x8 ka0 = *(const bf16x8*)&Kl[rk * KST + g * 8];
    bf16x8 ka1 = *(const bf16x8*)&Kl[rk * KST + 32 + g * 8];
    f32x4 t = __builtin_amdgcn_mfma_f32_16x16x32_bf16(ka0, qf0, zero, 0, 0, 0);
    st[wt] = __builtin_amdgcn_mfma_f32_16x16x32_bf16(ka1, qf1, t, 0, 0, 0);
  }

  // ---- masked exp + row-sum (q=c; w = 16wt+4g+r) ----
  float pv[3][4];
  float lsum = 0.f;
#pragma unroll
  for (int wt = 0; wt < 3; ++wt)
#pragma unroll
    for (int r = 0; r < 4; ++r) {
      int w = 16 * wt + 4 * g + r;
      int pos = tg - WIN + w;
      bool valid = (w >= c) && (w <= c + 32) && (pos >= 0) && (pos < T_LEN);
      float e = __expf(st[wt][r] * scale);
      pv[wt][r] = valid ? e : 0.f;
      lsum += pv[wt][r];
    }
  lsum += __shfl_xor(lsum, 16);
  lsum += __shfl_xor(lsum, 32);
  float inv = 1.f / lsum;

  // ---- write normalized P (bf16, stride 56) into the same per-wave region ----
  bf16* P = Qw;
#pragma unroll
  for (int wt = 0; wt < 3; ++wt) {
    bf16x2 p01, p23;
    p01[0] = (bf16)(pv[wt][0] * inv);
    p01[1] = (bf16)(pv[wt][1] * inv);
    p23[0] = (bf16)(pv[wt][2] * inv);
    p23[1] = (bf16)(pv[wt][3] * inv);
    *(bf16x2*)&P[c * 56 + 16 * wt + 4 * g]     = p01;
    *(bf16x2*)&P[c * 56 + 16 * wt + 4 * g + 2] = p23;
  }

  // ---- PV: O[16q][64d] ----
  bf16x8 pa0 = *(const bf16x8*)&P[c * 56 + 8 * g];
  int g1 = (g < 2) ? g : 1;
  bf16x8 pa1 = *(const bf16x8*)&P[c * 56 + 32 + 8 * g1];
  if (g >= 2) pa1 = __builtin_bit_cast(bf16x8, zu);  // w>=48 -> P=0

  f32x4 acc[4] = {zero, zero, zero, zero};
#pragma unroll
  for (int dt = 0; dt < 4; ++dt) {
    const unsigned short* vp = &Vt[(16 * dt + c) * NPT + 16 * wid + 8 * g];
    bf16x8 v0 = *(const bf16x8*)(vp);        // kh0: w = 8g+e
    bf16x8 v1 = *(const bf16x8*)(vp + 32);   // kh1: w = 32+8g+e
    acc[dt] = __builtin_amdgcn_mfma_f32_16x16x32_bf16(pa0, v0, acc[dt], 0, 0, 0);
    acc[dt] = __builtin_amdgcn_mfma_f32_16x16x32_bf16(pa1, v1, acc[dt], 0, 0, 0);
  }

  // ---- O to LDS (stride 72), coalesced store ----
  bf16* O = Qw;
#pragma unroll
  for (int dt = 0; dt < 4; ++dt)
#pragma unroll
    for (int r = 0; r < 4; ++r)
      O[(4 * g + r) * 72 + 16 * dt + c] = (bf16)acc[dt][r];

  bf16x8 o0 = *(const bf16x8*)&O[c * 72 + g * 8];
  bf16x8 o1 = *(const bf16x8*)&O[c * 72 + 32 + g * 8];
  bf16* orow = aout + (size_t)(base + tg + c) * 512 + h * 64;
  *(bf16x8*)(orow + g * 8) = o0;
  *(bf16x8*)(orow + 32 + g * 8) = o1;
}

// ---- proj GEMM + residual + LayerNorm fused ----
__global__ __launch_bounds__(512) void proj_ln_kernel(const bf16* __restrict__ A,
                                                      const bf16* __restrict__ Bw,
                                                      const float* __restrict__ X,
                                                      const float* __restrict__ gamma,
                                                      const float* __restrict__ beta,
                                                      float* __restrict__ out) {
  constexpr int K = 512, BK = 32, BM = 32;
  __shared__ __align__(16) bf16 As[BM * BK];
  __shared__ __align__(16) bf16 Bs[512 * BK];
  __shared__ __align__(16) float rsum[32][8];
  __shared__ __align__(16) float rsq[32][8];

  const int tid = threadIdx.x;
  const int w = tid >> 6;
  const int l = tid & 63;
  const int g = l >> 4;
  const int c = l & 15;
  int bid = blockIdx.x;
  bid = (bid & 7) * 32 + (bid >> 3);  // XCD swizzle: 256 = 32 x 8
  const int m0 = bid * BM;

  const f32x4 zero = {0.f, 0.f, 0.f, 0.f};
  f32x4 acc[2][4];
#pragma unroll
  for (int m = 0; m < 2; ++m)
#pragma unroll
    for (int n = 0; n < 4; ++n) acc[m][n] = zero;

  for (int k0 = 0; k0 < K; k0 += BK) {
    if (tid < 128)
      GLOAD16(A + (size_t)(m0 + (tid >> 2)) * K + k0 + (tid & 3) * 8, &As[tid * 8]);
#pragma unroll
    for (int j = 0; j < 4; ++j) {
      int tau = tid + 512 * j;
      GLOAD16(Bw + (size_t)(tau >> 2) * K + k0 + (tau & 3) * 8, &Bs[tau * 8]);
    }
    __syncthreads();
    bf16x8 af[2], bfv[4];
#pragma unroll
    for (int m = 0; m < 2; ++m)
      af[m] = *(const bf16x8*)&As[(m * 16 + c) * BK + 8 * g];
#pragma unroll
    for (int n = 0; n < 4; ++n)
      bfv[n] = *(const bf16x8*)&Bs[(w * 64 + n * 16 + c) * BK + 8 * g];
#pragma unroll
    for (int m = 0; m < 2; ++m)
#pragma unroll
      for (int n = 0; n < 4; ++n)
        acc[m][n] = __builtin_amdgcn_mfma_f32_16x16x32_bf16(af[m], bfv[n], acc[m][n], 0, 0, 0);
    __syncthreads();
  }

  const int col0 = w * 64 + c;
  float ps[2][4], ps2[2][4];
#pragma unroll
  for (int m = 0; m < 2; ++m)
#pragma unroll
    for (int r = 0; r < 4; ++r) {
      int row = m0 + m * 16 + 4 * g + r;
      float s = 0.f, s2 = 0.f;
#pragma unroll
      for (int n = 0; n < 4; ++n) {
        float y = acc[m][n][r] + X[(size_t)row * 512 + col0 + n * 16];
        acc[m][n][r] = y;
        s += y;
        s2 += y * y;
      }
      ps[m][r] = s;
      ps2[m][r] = s2;
    }
#pragma unroll
  for (int m = 0; m < 2; ++m)
#pragma unroll
    for (int r = 0; r < 4; ++r) {
      float s = ps[m][r], s2 = ps2[m][r];
      s += __shfl_xor(s, 1);  s2 += __shfl_xor(s2, 1);
      s += __shfl_xor(s, 2);  s2 += __shfl_xor(s2, 2);
      s += __shfl_xor(s, 4);  s2 += __shfl_xor(s2, 4);
      s += __shfl_xor(s, 8);  s2 += __shfl_xor(s2, 8);
      ps[m][r] = s;
      ps2[m][r] = s2;
    }
  if (c == 0) {
#pragma unroll
    for (int m = 0; m < 2; ++m)
#pragma unroll
      for (int r = 0; r < 4; ++r) {
        rsum[m * 16 + 4 * g + r][w] = ps[m][r];
        rsq[m * 16 + 4 * g + r][w] = ps2[m][r];
      }
  }
  __syncthreads();

  float gam[4], bet[4];
#pragma unroll
  for (int n = 0; n < 4; ++n) {
    gam[n] = gamma[col0 + n * 16];
    bet[n] = beta[col0 + n * 16];
  }
#pragma unroll
  for (int m = 0; m < 2; ++m)
#pragma unroll
    for (int r = 0; r < 4; ++r) {
      int rl = m * 16 + 4 * g + r;
      float4 s0 = *(const float4*)&rsum[rl][0];
      float4 s1 = *(const float4*)&rsum[rl][4];
      float4 q0 = *(const float4*)&rsq[rl][0];
      float4 q1 = *(const float4*)&rsq[rl][4];
      float sum = (s0.x + s0.y + s0.z + s0.w) + (s1.x + s1.y + s1.z + s1.w);
      float sq  = (q0.x + q0.y + q0.z + q0.w) + (q1.x + q1.y + q1.z + q1.w);
      float mu = sum * (1.f / 512.f);
      float var = sq * (1.f / 512.f) - mu * mu;
      float rs = rsqrtf(var + 1e-5f);
#pragma unroll
      for (int n = 0; n < 4; ++n)
        out[(size_t)(m0 + rl) * 512 + col0 + n * 16] =
            gam[n] * (acc[m][n][r] - mu) * rs + bet[n];
    }
}

extern "C" void kernel_launch(void* const* d_in, const int* in_sizes, int n_in,
                              void* d_out, int out_size, void* d_ws, size_t ws_size,
                              hipStream_t stream) {
  const float* x  = (const float*)d_in[0];
  const float* Wq = (const float*)d_in[1];
  const float* Wk = (const float*)d_in[2];
  const float* Wv = (const float*)d_in[3];
  const float* Wp = (const float*)d_in[4];
  const float* g  = (const float*)d_in[5];
  const float* be = (const float*)d_in[6];
  float* out = (float*)d_out;

  char* ws = (char*)d_ws;
  bf16* wqkv = (bf16*)(ws);                         // 1,572,864 B
  bf16* wpb  = (bf16*)(ws + 1572864);               //   524,288 B
  bf16* qkv  = (bf16*)(ws + 2097152);               // 25,165,824 B
  bf16* aout = (bf16*)(ws + 27262976);              // 8,388,608 B

  prep_kernel<<<512, 256, 0, stream>>>(Wq, Wk, Wv, Wp, wqkv, wpb);
  // QKV: M=8192, N=1536 -> 64 x 12 tiles (A cast in-kernel from fp32 x)
  gemm_qkv_kernel<<<64 * 12, 256, 0, stream>>>(x, wqkv, qkv);
  // attn: blocks = B(2) * H(8) * T/TCB(64) = 1024
  attn_kernel<<<1024, 256, 0, stream>>>(qkv, aout);
  // proj + residual + LN: 8192/32 = 256 blocks
  proj_ln_kernel<<<256, 512, 0, stream>>>(aout, wpb, x, g, be, out);
}

// Round 8
// 65.346 us; speedup vs baseline: 1.0037x; 1.0037x over previous
//
#include <hip/hip_runtime.h>
#include <hip/hip_bf16.h>
#include <stdint.h>

typedef __bf16 bf16;
typedef __attribute__((ext_vector_type(8))) __bf16 bf16x8;
typedef __attribute__((ext_vector_type(2))) __bf16 bf16x2;
typedef __attribute__((ext_vector_type(4))) float f32x4;
typedef __attribute__((ext_vector_type(4))) unsigned int u32x4;

#define GLOAD16(gsrc, ldst)                                              \
  __builtin_amdgcn_global_load_lds(                                      \
      (const __attribute__((address_space(1))) unsigned int*)(gsrc),     \
      (__attribute__((address_space(3))) unsigned int*)(ldst), 16, 0, 0)

static constexpr int T_LEN = 4096;
static constexpr int WIN = 16;

__device__ __forceinline__ bf16x8 cvt8(float4 a, float4 b) {
  bf16x8 o;
  o[0] = (bf16)a.x; o[1] = (bf16)a.y; o[2] = (bf16)a.z; o[3] = (bf16)a.w;
  o[4] = (bf16)b.x; o[5] = (bf16)b.y; o[6] = (bf16)b.z; o[7] = (bf16)b.w;
  return o;
}

// ---- cast weights: Wq,Wk,Wv -> wqkv[1536][512], Wp -> wpb[512][512] ----
__global__ __launch_bounds__(256) void prep_kernel(const float* __restrict__ wq,
                                                   const float* __restrict__ wk,
                                                   const float* __restrict__ wv,
                                                   const float* __restrict__ wp,
                                                   bf16* __restrict__ wqkv,
                                                   bf16* __restrict__ wpb) {
  int i = blockIdx.x * 256 + threadIdx.x;  // 131072 threads
  int which = i >> 15;
  int j = i & 32767;
  const float* src = (which == 0) ? wq : (which == 1) ? wk : (which == 2) ? wv : wp;
  bf16* dst = (which < 3) ? (wqkv + (size_t)which * 512 * 512) : wpb;
  const float4* s4 = (const float4*)src + (size_t)j * 2;
  ((bf16x8*)dst)[j] = cvt8(s4[0], s4[1]);
}

// ---- QKV GEMM, 2-phase prefetch double-buffer ----
// C[m][n] = sum_k x[m][k] * Bw[n][k]; A cast fp32->bf16 via regs (issue-early/write-late)
__global__ __launch_bounds__(256) void gemm_qkv_kernel(const float* __restrict__ Xf,
                                                       const bf16* __restrict__ Bw,
                                                       bf16* __restrict__ Cb) {
  constexpr int K = 512, BK = 32, NIT = K / BK;  // 16
  __shared__ __align__(16) bf16 As[2][128 * BK];
  __shared__ __align__(16) bf16 Bs[2][128 * BK];
  const int tid = threadIdx.x;
  const int l = tid & 63;
  const int w = tid >> 6;
  int bid = blockIdx.x;
  bid = (bid & 7) * 96 + (bid >> 3);  // XCD swizzle (768 = 8*96)
  const int m0 = (bid / 12) * 128;
  const int n0 = (bid % 12) * 128;
  const int arow = tid >> 2;
  const int acol = (tid & 3) * 8;
  const float* Ag = Xf + (size_t)(m0 + arow) * K + acol;
  const bf16* Bg = Bw + (size_t)(n0 + arow) * K + acol;

  // prologue: stage tile 0
  GLOAD16(Bg,          &Bs[0][tid * 8]);
  GLOAD16(Bg + 64 * K, &Bs[0][tid * 8 + 2048]);
  {
    const float4* s0 = (const float4*)(Ag);
    const float4* s1 = (const float4*)(Ag + 64 * K);
    float4 a0 = s0[0], a1 = s0[1], b0 = s1[0], b1 = s1[1];
    *(bf16x8*)&As[0][tid * 8] = cvt8(a0, a1);
    *(bf16x8*)&As[0][tid * 8 + 2048] = cvt8(b0, b1);
  }
  __syncthreads();

  const f32x4 zero = {0.f, 0.f, 0.f, 0.f};
  f32x4 acc[4][4];
#pragma unroll
  for (int i = 0; i < 4; ++i)
#pragma unroll
    for (int j = 0; j < 4; ++j) acc[i][j] = zero;

  const int wm = (w >> 1) * 64;
  const int wn = (w & 1) * 64;
  const int frow = l & 15;
  const int fcol = (l >> 4) * 8;

  int cur = 0;
#pragma unroll 1
  for (int t = 0; t < NIT; ++t) {
    const int nxt = cur ^ 1;
    float4 pa0, pa1, pb0, pb1;
    const bool pref = (t + 1 < NIT);
    if (pref) {
      const int k1 = (t + 1) * BK;
      GLOAD16(Bg + k1,          &Bs[nxt][tid * 8]);
      GLOAD16(Bg + 64 * K + k1, &Bs[nxt][tid * 8 + 2048]);
      const float4* s0 = (const float4*)(Ag + k1);
      const float4* s1 = (const float4*)(Ag + 64 * K + k1);
      pa0 = s0[0]; pa1 = s0[1]; pb0 = s1[0]; pb1 = s1[1];
    }
    bf16x8 af[4], bfr[4];
#pragma unroll
    for (int mi = 0; mi < 4; ++mi)
      af[mi] = *(const bf16x8*)&As[cur][(wm + mi * 16 + frow) * BK + fcol];
#pragma unroll
    for (int ni = 0; ni < 4; ++ni)
      bfr[ni] = *(const bf16x8*)&Bs[cur][(wn + ni * 16 + frow) * BK + fcol];
#pragma unroll
    for (int mi = 0; mi < 4; ++mi)
#pragma unroll
      for (int ni = 0; ni < 4; ++ni)
        acc[mi][ni] = __builtin_amdgcn_mfma_f32_16x16x32_bf16(af[mi], bfr[ni], acc[mi][ni], 0, 0, 0);
    if (pref) {  // write-late: waits only on the fp32 A loads
      *(bf16x8*)&As[nxt][tid * 8] = cvt8(pa0, pa1);
      *(bf16x8*)&As[nxt][tid * 8 + 2048] = cvt8(pb0, pb1);
    }
    __syncthreads();  // drains vmcnt (B gload) + lgkm; gates buffer swap
    cur = nxt;
  }

  const int r0 = (l >> 4) * 4;
  const int c0 = l & 15;
#pragma unroll
  for (int mi = 0; mi < 4; ++mi)
#pragma unroll
    for (int ni = 0; ni < 4; ++ni) {
      int row = m0 + wm + mi * 16 + r0;
      int col = n0 + wn + ni * 16 + c0;
#pragma unroll
      for (int r = 0; r < 4; ++r)
        Cb[(size_t)(row + r) * 1536 + col] = (bf16)acc[mi][ni][r];
    }
}

// ---- local attention, MFMA-based; K row-major, V transposed, Q via LDS ----
static constexpr int TCB = 64;
static constexpr int NP = 96;
static constexpr int KST = 72;
static constexpr int NPT = 112;  // Vt col count (96 window + 16 zero halo)

__global__ __launch_bounds__(256) void attn_kernel(const bf16* __restrict__ qkv,
                                                   bf16* __restrict__ aout) {
  __shared__ __align__(16) bf16 Kl[NP * KST];
  __shared__ __align__(16) unsigned short Vt[64 * NPT];  // V^T[d][p]
  __shared__ __align__(16) bf16 QPO[4 * 16 * 72];  // per-wave: Q[16][72] -> P[16][56] -> O[16][72]

  const int tid = threadIdx.x;
  const int wid = tid >> 6;
  const int l = tid & 63;
  const int g = l >> 4;
  const int c = l & 15;

  const int bid = blockIdx.x;  // 1024 = 2 * 8 * 64
  const int chunk = bid & 63;
  const int h = (bid >> 6) & 7;
  const int b = bid >> 9;
  const int t0 = chunk * TCB;
  const int base = b * T_LEN;

  // ---- stage K row-major, V transposed ----
#pragma unroll
  for (int i = 0; i < 3; ++i) {
    int task = tid + i * 256;  // 768 = 96 pos x 8 col-chunks
    int p = task >> 3;
    int c8 = (task & 7) * 8;
    int pg = min(max(t0 - WIN + p, 0), T_LEN - 1);
    const bf16* kr = qkv + (size_t)(base + pg) * 1536 + 512 + h * 64 + c8;
    const bf16* vr = qkv + (size_t)(base + pg) * 1536 + 1024 + h * 64 + c8;
    *(bf16x8*)&Kl[p * KST + c8] = *(const bf16x8*)kr;
    bf16x8 vv = *(const bf16x8*)vr;
#pragma unroll
    for (int e = 0; e < 8; ++e)
      Vt[(c8 + e) * NPT + p] = ((const unsigned short*)&vv)[e];
  }
  // ---- stage Q (coalesced) into per-wave overlay regions ----
#pragma unroll
  for (int i = 0; i < 2; ++i) {
    int task = tid + i * 256;  // 512 = 64 rows x 8 chunks
    int p = task >> 3;
    int c8 = (task & 7) * 8;
    const bf16* qr = qkv + (size_t)(base + t0 + p) * 1536 + h * 64 + c8;
    *(bf16x8*)&QPO[(p >> 4) * 1152 + (p & 15) * 72 + c8] = *(const bf16x8*)qr;
  }
  // zero-fill Vt halo cols p=96..111 (read where P=0; must be finite)
  {
    int d = tid >> 2;
    int p0 = 96 + (tid & 3) * 4;
    *(uint2*)&Vt[d * NPT + p0] = make_uint2(0u, 0u);
  }
  __syncthreads();

  const int tg = t0 + wid * 16;
  const float scale = 0.125f;  // 64^-0.5

  // ---- Q fragments from LDS: k-map (g,e) -> d = 32*kh + 8g + e ----
  bf16* Qw = &QPO[wid * 1152];
  bf16x8 qf0 = *(const bf16x8*)&Qw[c * 72 + g * 8];
  bf16x8 qf1 = *(const bf16x8*)&Qw[c * 72 + 32 + g * 8];

  const f32x4 zero = {0.f, 0.f, 0.f, 0.f};
  const u32x4 zu = {0u, 0u, 0u, 0u};

  // ---- S^T = K @ Q^T ----
  f32x4 st[3];
#pragma unroll
  for (int wt = 0; wt < 3; ++wt) {
    int rk = 16 * wid + 16 * wt + c;
    bf16x8 ka0 = *(const bf16x8*)&Kl[rk * KST + g * 8];
    bf16x8 ka1 = *(const bf16x8*)&Kl[rk * KST + 32 + g * 8];
    f32x4 t = __builtin_amdgcn_mfma_f32_16x16x32_bf16(ka0, qf0, zero, 0, 0, 0);
    st[wt] = __builtin_amdgcn_mfma_f32_16x16x32_bf16(ka1, qf1, t, 0, 0, 0);
  }

  // ---- masked exp + row-sum (q=c; w = 16wt+4g+r) ----
  float pv[3][4];
  float lsum = 0.f;
#pragma unroll
  for (int wt = 0; wt < 3; ++wt)
#pragma unroll
    for (int r = 0; r < 4; ++r) {
      int w = 16 * wt + 4 * g + r;
      int pos = tg - WIN + w;
      bool valid = (w >= c) && (w <= c + 32) && (pos >= 0) && (pos < T_LEN);
      float e = __expf(st[wt][r] * scale);
      pv[wt][r] = valid ? e : 0.f;
      lsum += pv[wt][r];
    }
  lsum += __shfl_xor(lsum, 16);
  lsum += __shfl_xor(lsum, 32);
  float inv = 1.f / lsum;

  // ---- write normalized P (bf16, stride 56) into the same per-wave region ----
  bf16* P = Qw;
#pragma unroll
  for (int wt = 0; wt < 3; ++wt) {
    bf16x2 p01, p23;
    p01[0] = (bf16)(pv[wt][0] * inv);
    p01[1] = (bf16)(pv[wt][1] * inv);
    p23[0] = (bf16)(pv[wt][2] * inv);
    p23[1] = (bf16)(pv[wt][3] * inv);
    *(bf16x2*)&P[c * 56 + 16 * wt + 4 * g]     = p01;
    *(bf16x2*)&P[c * 56 + 16 * wt + 4 * g + 2] = p23;
  }

  // ---- PV: O[16q][64d] ----
  bf16x8 pa0 = *(const bf16x8*)&P[c * 56 + 8 * g];
  int g1 = (g < 2) ? g : 1;
  bf16x8 pa1 = *(const bf16x8*)&P[c * 56 + 32 + 8 * g1];
  if (g >= 2) pa1 = __builtin_bit_cast(bf16x8, zu);  // w>=48 -> P=0

  f32x4 acc[4] = {zero, zero, zero, zero};
#pragma unroll
  for (int dt = 0; dt < 4; ++dt) {
    const unsigned short* vp = &Vt[(16 * dt + c) * NPT + 16 * wid + 8 * g];
    bf16x8 v0 = *(const bf16x8*)(vp);        // kh0: w = 8g+e
    bf16x8 v1 = *(const bf16x8*)(vp + 32);   // kh1: w = 32+8g+e
    acc[dt] = __builtin_amdgcn_mfma_f32_16x16x32_bf16(pa0, v0, acc[dt], 0, 0, 0);
    acc[dt] = __builtin_amdgcn_mfma_f32_16x16x32_bf16(pa1, v1, acc[dt], 0, 0, 0);
  }

  // ---- O to LDS (stride 72), coalesced store ----
  bf16* O = Qw;
#pragma unroll
  for (int dt = 0; dt < 4; ++dt)
#pragma unroll
    for (int r = 0; r < 4; ++r)
      O[(4 * g + r) * 72 + 16 * dt + c] = (bf16)acc[dt][r];

  bf16x8 o0 = *(const bf16x8*)&O[c * 72 + g * 8];
  bf16x8 o1 = *(const bf16x8*)&O[c * 72 + 32 + g * 8];
  bf16* orow = aout + (size_t)(base + tg + c) * 512 + h * 64;
  *(bf16x8*)(orow + g * 8) = o0;
  *(bf16x8*)(orow + 32 + g * 8) = o1;
}

// ---- proj GEMM + residual + LayerNorm fused, 2-phase prefetch ----
__global__ __launch_bounds__(512) void proj_ln_kernel(const bf16* __restrict__ A,
                                                      const bf16* __restrict__ Bw,
                                                      const float* __restrict__ X,
                                                      const float* __restrict__ gamma,
                                                      const float* __restrict__ beta,
                                                      float* __restrict__ out) {
  constexpr int K = 512, BK = 32, BM = 32, NIT = K / BK;
  __shared__ __align__(16) bf16 As[2][BM * BK];
  __shared__ __align__(16) bf16 Bs[2][512 * BK];
  __shared__ __align__(16) float rsum[32][8];
  __shared__ __align__(16) float rsq[32][8];

  const int tid = threadIdx.x;
  const int w = tid >> 6;
  const int l = tid & 63;
  const int g = l >> 4;
  const int c = l & 15;
  int bid = blockIdx.x;
  bid = (bid & 7) * 32 + (bid >> 3);  // XCD swizzle: 256 = 8*32
  const int m0 = bid * BM;

  // prologue: stage tile 0
  if (tid < 128)
    GLOAD16(A + (size_t)(m0 + (tid >> 2)) * K + (tid & 3) * 8, &As[0][tid * 8]);
#pragma unroll
  for (int j = 0; j < 4; ++j) {
    int tau = tid + 512 * j;
    GLOAD16(Bw + (size_t)(tau >> 2) * K + (tau & 3) * 8, &Bs[0][tau * 8]);
  }
  __syncthreads();

  const f32x4 zero = {0.f, 0.f, 0.f, 0.f};
  f32x4 acc[2][4];
#pragma unroll
  for (int m = 0; m < 2; ++m)
#pragma unroll
    for (int n = 0; n < 4; ++n) acc[m][n] = zero;

  int cur = 0;
#pragma unroll 1
  for (int t = 0; t < NIT; ++t) {
    const int nxt = cur ^ 1;
    if (t + 1 < NIT) {
      const int k1 = (t + 1) * BK;
      if (tid < 128)
        GLOAD16(A + (size_t)(m0 + (tid >> 2)) * K + k1 + (tid & 3) * 8, &As[nxt][tid * 8]);
#pragma unroll
      for (int j = 0; j < 4; ++j) {
        int tau = tid + 512 * j;
        GLOAD16(Bw + (size_t)(tau >> 2) * K + k1 + (tau & 3) * 8, &Bs[nxt][tau * 8]);
      }
    }
    bf16x8 af[2], bfv[4];
#pragma unroll
    for (int m = 0; m < 2; ++m)
      af[m] = *(const bf16x8*)&As[cur][(m * 16 + c) * BK + 8 * g];
#pragma unroll
    for (int n = 0; n < 4; ++n)
      bfv[n] = *(const bf16x8*)&Bs[cur][(w * 64 + n * 16 + c) * BK + 8 * g];
#pragma unroll
    for (int m = 0; m < 2; ++m)
#pragma unroll
      for (int n = 0; n < 4; ++n)
        acc[m][n] = __builtin_amdgcn_mfma_f32_16x16x32_bf16(af[m], bfv[n], acc[m][n], 0, 0, 0);
    __syncthreads();
    cur = nxt;
  }

  const int col0 = w * 64 + c;
  float ps[2][4], ps2[2][4];
#pragma unroll
  for (int m = 0; m < 2; ++m)
#pragma unroll
    for (int r = 0; r < 4; ++r) {
      int row = m0 + m * 16 + 4 * g + r;
      float s = 0.f, s2 = 0.f;
#pragma unroll
      for (int n = 0; n < 4; ++n) {
        float y = acc[m][n][r] + X[(size_t)row * 512 + col0 + n * 16];
        acc[m][n][r] = y;
        s += y;
        s2 += y * y;
      }
      ps[m][r] = s;
      ps2[m][r] = s2;
    }
#pragma unroll
  for (int m = 0; m < 2; ++m)
#pragma unroll
    for (int r = 0; r < 4; ++r) {
      float s = ps[m][r], s2 = ps2[m][r];
      s += __shfl_xor(s, 1);  s2 += __shfl_xor(s2, 1);
      s += __shfl_xor(s, 2);  s2 += __shfl_xor(s2, 2);
      s += __shfl_xor(s, 4);  s2 += __shfl_xor(s2, 4);
      s += __shfl_xor(s, 8);  s2 += __shfl_xor(s2, 8);
      ps[m][r] = s;
      ps2[m][r] = s2;
    }
  if (c == 0) {
#pragma unroll
    for (int m = 0; m < 2; ++m)
#pragma unroll
      for (int r = 0; r < 4; ++r) {
        rsum[m * 16 + 4 * g + r][w] = ps[m][r];
        rsq[m * 16 + 4 * g + r][w] = ps2[m][r];
      }
  }
  __syncthreads();

  float gam[4], bet[4];
#pragma unroll
  for (int n = 0; n < 4; ++n) {
    gam[n] = gamma[col0 + n * 16];
    bet[n] = beta[col0 + n * 16];
  }
#pragma unroll
  for (int m = 0; m < 2; ++m)
#pragma unroll
    for (int r = 0; r < 4; ++r) {
      int rl = m * 16 + 4 * g + r;
      float4 s0 = *(const float4*)&rsum[rl][0];
      float4 s1 = *(const float4*)&rsum[rl][4];
      float4 q0 = *(const float4*)&rsq[rl][0];
      float4 q1 = *(const float4*)&rsq[rl][4];
      float sum = (s0.x + s0.y + s0.z + s0.w) + (s1.x + s1.y + s1.z + s1.w);
      float sq  = (q0.x + q0.y + q0.z + q0.w) + (q1.x + q1.y + q1.z + q1.w);
      float mu = sum * (1.f / 512.f);
      float var = sq * (1.f / 512.f) - mu * mu;
      float rs = rsqrtf(var + 1e-5f);
#pragma unroll
      for (int n = 0; n < 4; ++n)
        out[(size_t)(m0 + rl) * 512 + col0 + n * 16] =
            gam[n] * (acc[m][n][r] - mu) * rs + bet[n];
    }
}

extern "C" void kernel_launch(void* const* d_in, const int* in_sizes, int n_in,
                              void* d_out, int out_size, void* d_ws, size_t ws_size,
                              hipStream_t stream) {
  const float* x  = (const float*)d_in[0];
  const float* Wq = (const float*)d_in[1];
  const float* Wk = (const float*)d_in[2];
  const float* Wv = (const float*)d_in[3];
  const float* Wp = (const float*)d_in[4];
  const float* g  = (const float*)d_in[5];
  const float* be = (const float*)d_in[6];
  float* out = (float*)d_out;

  char* ws = (char*)d_ws;
  bf16* wqkv = (bf16*)(ws);                         // 1,572,864 B
  bf16* wpb  = (bf16*)(ws + 1572864);               //   524,288 B
  bf16* qkv  = (bf16*)(ws + 2097152);               // 25,165,824 B
  bf16* aout = (bf16*)(ws + 27262976);              // 8,388,608 B

  prep_kernel<<<512, 256, 0, stream>>>(Wq, Wk, Wv, Wp, wqkv, wpb);
  // QKV: M=8192, N=1536 -> 64 x 12 tiles (A cast in-kernel from fp32 x)
  gemm_qkv_kernel<<<64 * 12, 256, 0, stream>>>(x, wqkv, qkv);
  // attn: blocks = B(2) * H(8) * T/TCB(64) = 1024
  attn_kernel<<<1024, 256, 0, stream>>>(qkv, aout);
  // proj + residual + LN: 8192/32 = 256 blocks
  proj_ln_kernel<<<256, 512, 0, stream>>>(aout, wpb, x, g, be, out);
}